// Round 9
// baseline (391.181 us; speedup 1.0000x reference)
//
#include <hip/hip_runtime.h>

// ChamferLoss: B=4, N=M=8192, D=3, fp32. Scalar out.
// MFMA split-f16 (validated EXACT r6-r8): one 32x32x16_f16 MFMA emits a full
// 32x32 tile of d[n,m] = qn + rn - 2 q.r via 13 K-slots. Two row-min passes
// (dir = blockIdx.z). r8 fixed LDS conflicts (17.8M -> 0). r9:
//  1) col-tiles processed in PAIRS: rm = min3(rm, dA[i], dB[i]) -> halves
//     loop VALU (64 min3 vs 128 min per 2048 pairs).
//  2) explicit B-frag prefetch (software pipeline) to cover lgkmcnt at the
//     ~2 waves/SIMD occupancy the register budget allows.

#define BATCH   4
#define NPTS    8192
#define TPB     256
#define CSLICE  1024                 // ref columns per block
#define NT      4                    // row-tiles per wave
#define NROWS   (4 * NT * 32)        // 512 query rows per block
#define MT      (CSLICE / 32)        // 32 col-tiles per block
#define SLICES  (NPTS / CSLICE)      // 8
#define BANDS   (NPTS / NROWS)       // 16

typedef _Float16 h8   __attribute__((ext_vector_type(8)));
typedef float    f16v __attribute__((ext_vector_type(16)));

__device__ __forceinline__ void split16(float v, _Float16& hi, _Float16& lo) {
    hi = (_Float16)v;
    lo = (_Float16)(v - (float)hi);
}

__global__ __launch_bounds__(TPB) void chamfer_mfma(const float* __restrict__ xg,
                                                    const float* __restrict__ yg,
                                                    float* __restrict__ partial) {
    __shared__ h8 bfrag[CSLICE * 2];          // 32 KB, de-interleaved (conflict-free)
    __shared__ float rmf[NROWS];              // 2 KB rowmin

    const int tid   = threadIdx.x;
    const int band  = blockIdx.x;             // [0,16)
    const int slice = blockIdx.y & (SLICES - 1);
    const int b     = blockIdx.y >> 3;        // SLICES == 8
    const int dir   = blockIdx.z;
    const int lane  = tid & 63, wave = tid >> 6;
    const int col   = lane & 31, hv = lane >> 5;

    const float* q = dir ? yg : xg;           // query side (rows, register rowmin)
    const float* r = dir ? xg : yg;           // reference side (cols, LDS B-frags)

    // ---- stage B fragments: 4 ref points per thread, de-interleaved layout ----
    const float* rbase = r + ((size_t)b * NPTS + slice * CSLICE) * 3;
#pragma unroll
    for (int i = 0; i < CSLICE / TPB; ++i) {
        const int p = tid + i * TPB;
        float r0 = rbase[p * 3 + 0], r1 = rbase[p * 3 + 1], r2 = rbase[p * 3 + 2];
        _Float16 h0, l0, h1, l1, h2, l2, rnh, rnl;
        split16(-2.0f * r0, h0, l0);
        split16(-2.0f * r1, h1, l1);
        split16(-2.0f * r2, h2, l2);
        split16(fmaf(r0, r0, fmaf(r1, r1, r2 * r2)), rnh, rnl);
        const int base = (p >> 5) * 64 + (p & 31);            // [tile][hv][col]
        bfrag[base]      = (h8){h0, h1, h2, h0, h1, h2, l0, l1};            // k0..7
        bfrag[base + 32] = (h8){l2, (_Float16)1.0f, (_Float16)1.0f, rnh, rnl,
                                (_Float16)0.0f, (_Float16)0.0f, (_Float16)0.0f}; // k8..15
    }

    // ---- A fragments: NT row-tiles per wave ----
    h8 af[NT];
#pragma unroll
    for (int t = 0; t < NT; ++t) {
        const int n = band * NROWS + (wave * NT + t) * 32 + col;
        const float* qp = q + ((size_t)b * NPTS + n) * 3;
        float x0 = qp[0], x1 = qp[1], x2 = qp[2];
        _Float16 h0, l0, h1, l1, h2, l2, qnh, qnl;
        split16(x0, h0, l0);
        split16(x1, h1, l1);
        split16(x2, h2, l2);
        split16(fmaf(x0, x0, fmaf(x1, x1, x2 * x2)), qnh, qnl);
        h8 a0 = {h0, h1, h2, l0, l1, l2, h0, h1};                           // k0..7
        h8 a1 = {h2, qnh, qnl, (_Float16)1.0f, (_Float16)1.0f,
                 (_Float16)0.0f, (_Float16)0.0f, (_Float16)0.0f};           // k8..15
        af[t] = hv ? a1 : a0;
    }
    __syncthreads();

    const f16v zf = {};
    f16v rm[NT];
#pragma unroll
    for (int t = 0; t < NT; ++t)
#pragma unroll
        for (int i = 0; i < 16; ++i) rm[t][i] = 3.0e38f;

    // ---- main loop: tile-pairs, explicit prefetch, min3 accumulation ----
    h8 bfA = bfrag[lane];
    h8 bfB = bfrag[64 + lane];
#pragma unroll 4
    for (int mt = 0; mt < MT; mt += 2) {
        h8 nA, nB;
        if (mt + 2 < MT) {
            nA = bfrag[(mt + 2) * 64 + lane];   // prefetch next pair early
            nB = bfrag[(mt + 3) * 64 + lane];
        }
#pragma unroll
        for (int t = 0; t < NT; ++t) {
            f16v dA = __builtin_amdgcn_mfma_f32_32x32x16_f16(af[t], bfA, zf, 0, 0, 0);
            f16v dB = __builtin_amdgcn_mfma_f32_32x32x16_f16(af[t], bfB, zf, 0, 0, 0);
#pragma unroll
            for (int i = 0; i < 16; ++i)
                rm[t][i] = fminf(rm[t][i], fminf(dA[i], dB[i]));   // -> v_min3_f32
        }
        bfA = nA;
        bfB = nB;
    }

    // ---- epilogue: butterfly min over the 32 cols (exact), plain stores ----
#pragma unroll
    for (int t = 0; t < NT; ++t) {
#pragma unroll
        for (int s = 1; s < 32; s <<= 1)
#pragma unroll
            for (int i = 0; i < 16; ++i)
                rm[t][i] = fminf(rm[t][i], __shfl_xor(rm[t][i], s, 64));
        if (col == 0) {
#pragma unroll
            for (int i = 0; i < 16; ++i) {
                const int row = (i & 3) + 8 * (i >> 2) + 4 * hv;  // m74/m101 C/D map
                rmf[(wave * NT + t) * 32 + row] = rm[t][i];
            }
        }
    }
    __syncthreads();

    float* pp = partial + ((size_t)(dir * BATCH + b) * SLICES + slice) * NPTS
                        + band * NROWS;
    pp[tid]       = rmf[tid];                  // coalesced
    pp[tid + 256] = rmf[tid + 256];
}

__global__ __launch_bounds__(TPB) void chamfer_reduce(const float* __restrict__ partial,
                                                      float* __restrict__ out) {
    const int tid = threadIdx.x;
    const int g   = blockIdx.x * TPB + tid;   // [0, 2*BATCH*NPTS)
    const int db  = g >> 13;                  // (dir*BATCH + b)
    const int n   = g & (NPTS - 1);

    const float* p = partial + (size_t)db * SLICES * NPTS + n;
    float v = 3.0e38f;
#pragma unroll
    for (int s = 0; s < SLICES; ++s)
        v = fminf(v, p[(size_t)s * NPTS]);    // coalesced across threads

    float w = v;
#pragma unroll
    for (int off = 32; off > 0; off >>= 1)
        w += __shfl_down(w, off, 64);
    __shared__ float ss[TPB / 64];
    if ((tid & 63) == 0) ss[tid >> 6] = w;
    __syncthreads();
    if (tid == 0)
        atomicAdd(out, (ss[0] + ss[1] + ss[2] + ss[3]) * (1.0f / (float)(BATCH * NPTS)));
}

extern "C" void kernel_launch(void* const* d_in, const int* in_sizes, int n_in,
                              void* d_out, int out_size, void* d_ws, size_t ws_size,
                              hipStream_t stream) {
    const float* x = (const float*)d_in[0];
    const float* y = (const float*)d_in[1];
    float* out = (float*)d_out;
    float* partial = (float*)d_ws;            // 2*4*8*8192*4 = 2 MB

    hipMemsetAsync(out, 0, sizeof(float), stream);
    chamfer_mfma<<<dim3(BANDS, BATCH * SLICES, 2), TPB, 0, stream>>>(x, y, partial);
    chamfer_reduce<<<dim3(2 * BATCH * NPTS / TPB), TPB, 0, stream>>>(partial, out);
}

// Round 10
// 91.804 us; speedup vs baseline: 4.2610x; 4.2610x over previous
//
#include <hip/hip_runtime.h>

// ChamferLoss: B=4, N=M=8192, D=3, fp32. Scalar out.
// MFMA split-f16 (validated EXACT r6-r9): one 32x32x16_f16 MFMA emits a full
// 32x32 tile of d[n,m] = qn + rn - 2 q.r via 13 K-slots. Two row-min passes
// (dir = blockIdx.z). r8 fixed LDS conflicts (0). r9's min3 attempt spilled
// (VGPR 256, 1.1GB scratch traffic) from unroll-4 + prefetch regs. r10 =
// min3 with the pressure removed:
//   NT=2 (rm = 32 regs), tile-PAIRS with v_min3_f32 accumulation,
//   NO explicit prefetch, NO unroll pragma. Loop VALU/wave: 512 min3
//   (r8: 2048 v_min). Target VGPR <= 128, 4 waves/SIMD.

#define BATCH   4
#define NPTS    8192
#define TPB     256
#define CSLICE  1024                 // ref columns per block
#define NT      2                    // row-tiles per wave
#define NROWS   (4 * NT * 32)        // 256 query rows per block
#define MT      (CSLICE / 32)        // 32 col-tiles per block
#define SLICES  (NPTS / CSLICE)      // 8
#define BANDS   (NPTS / NROWS)       // 32

typedef _Float16 h8   __attribute__((ext_vector_type(8)));
typedef float    f16v __attribute__((ext_vector_type(16)));

__device__ __forceinline__ void split16(float v, _Float16& hi, _Float16& lo) {
    hi = (_Float16)v;
    lo = (_Float16)(v - (float)hi);
}

__global__ __launch_bounds__(TPB) void chamfer_mfma(const float* __restrict__ xg,
                                                    const float* __restrict__ yg,
                                                    float* __restrict__ partial) {
    __shared__ h8 bfrag[CSLICE * 2];          // 32 KB, de-interleaved (conflict-free)
    __shared__ float rmf[NROWS];              // 1 KB rowmin

    const int tid   = threadIdx.x;
    const int band  = blockIdx.x;             // [0,32)
    const int slice = blockIdx.y & (SLICES - 1);
    const int b     = blockIdx.y >> 3;        // SLICES == 8
    const int dir   = blockIdx.z;
    const int lane  = tid & 63, wave = tid >> 6;
    const int col   = lane & 31, hv = lane >> 5;

    const float* q = dir ? yg : xg;           // query side (rows, register rowmin)
    const float* r = dir ? xg : yg;           // reference side (cols, LDS B-frags)

    // ---- stage B fragments: 4 ref points per thread, de-interleaved layout ----
    const float* rbase = r + ((size_t)b * NPTS + slice * CSLICE) * 3;
#pragma unroll
    for (int i = 0; i < CSLICE / TPB; ++i) {
        const int p = tid + i * TPB;
        float r0 = rbase[p * 3 + 0], r1 = rbase[p * 3 + 1], r2 = rbase[p * 3 + 2];
        _Float16 h0, l0, h1, l1, h2, l2, rnh, rnl;
        split16(-2.0f * r0, h0, l0);
        split16(-2.0f * r1, h1, l1);
        split16(-2.0f * r2, h2, l2);
        split16(fmaf(r0, r0, fmaf(r1, r1, r2 * r2)), rnh, rnl);
        const int base = (p >> 5) * 64 + (p & 31);            // [tile][hv][col]
        bfrag[base]      = (h8){h0, h1, h2, h0, h1, h2, l0, l1};            // k0..7
        bfrag[base + 32] = (h8){l2, (_Float16)1.0f, (_Float16)1.0f, rnh, rnl,
                                (_Float16)0.0f, (_Float16)0.0f, (_Float16)0.0f}; // k8..15
    }

    // ---- A fragments: NT row-tiles per wave ----
    h8 af[NT];
#pragma unroll
    for (int t = 0; t < NT; ++t) {
        const int n = band * NROWS + (wave * NT + t) * 32 + col;
        const float* qp = q + ((size_t)b * NPTS + n) * 3;
        float x0 = qp[0], x1 = qp[1], x2 = qp[2];
        _Float16 h0, l0, h1, l1, h2, l2, qnh, qnl;
        split16(x0, h0, l0);
        split16(x1, h1, l1);
        split16(x2, h2, l2);
        split16(fmaf(x0, x0, fmaf(x1, x1, x2 * x2)), qnh, qnl);
        h8 a0 = {h0, h1, h2, l0, l1, l2, h0, h1};                           // k0..7
        h8 a1 = {h2, qnh, qnl, (_Float16)1.0f, (_Float16)1.0f,
                 (_Float16)0.0f, (_Float16)0.0f, (_Float16)0.0f};           // k8..15
        af[t] = hv ? a1 : a0;
    }
    __syncthreads();

    const f16v zf = {};
    f16v rm[NT];
#pragma unroll
    for (int t = 0; t < NT; ++t)
#pragma unroll
        for (int i = 0; i < 16; ++i) rm[t][i] = 3.0e38f;

    // ---- main loop: tile-pairs + min3; no prefetch regs, no unroll pragma ----
    for (int mt = 0; mt < MT; mt += 2) {
        const h8 bfA = bfrag[mt * 64 + lane];       // contiguous 16B/lane reads
        const h8 bfB = bfrag[(mt + 1) * 64 + lane]; // (conflict-free, r8-verified)
#pragma unroll
        for (int t = 0; t < NT; ++t) {
            f16v dA = __builtin_amdgcn_mfma_f32_32x32x16_f16(af[t], bfA, zf, 0, 0, 0);
            f16v dB = __builtin_amdgcn_mfma_f32_32x32x16_f16(af[t], bfB, zf, 0, 0, 0);
#pragma unroll
            for (int i = 0; i < 16; ++i)
                rm[t][i] = fminf(rm[t][i], fminf(dA[i], dB[i]));   // v_min3_f32
        }
    }

    // ---- epilogue: butterfly min over the 32 cols (exact), plain stores ----
#pragma unroll
    for (int t = 0; t < NT; ++t) {
#pragma unroll
        for (int s = 1; s < 32; s <<= 1)
#pragma unroll
            for (int i = 0; i < 16; ++i)
                rm[t][i] = fminf(rm[t][i], __shfl_xor(rm[t][i], s, 64));
        if (col == 0) {
#pragma unroll
            for (int i = 0; i < 16; ++i) {
                const int row = (i & 3) + 8 * (i >> 2) + 4 * hv;  // m74/m101 C/D map
                rmf[(wave * NT + t) * 32 + row] = rm[t][i];
            }
        }
    }
    __syncthreads();

    float* pp = partial + ((size_t)(dir * BATCH + b) * SLICES + slice) * NPTS
                        + band * NROWS;
    pp[tid] = rmf[tid];                        // NROWS == TPB, coalesced
}

__global__ __launch_bounds__(TPB) void chamfer_reduce(const float* __restrict__ partial,
                                                      float* __restrict__ out) {
    const int tid = threadIdx.x;
    const int g   = blockIdx.x * TPB + tid;   // [0, 2*BATCH*NPTS)
    const int db  = g >> 13;                  // (dir*BATCH + b)
    const int n   = g & (NPTS - 1);

    const float* p = partial + (size_t)db * SLICES * NPTS + n;
    float v = 3.0e38f;
#pragma unroll
    for (int s = 0; s < SLICES; ++s)
        v = fminf(v, p[(size_t)s * NPTS]);    // coalesced across threads

    float w = v;
#pragma unroll
    for (int off = 32; off > 0; off >>= 1)
        w += __shfl_down(w, off, 64);
    __shared__ float ss[TPB / 64];
    if ((tid & 63) == 0) ss[tid >> 6] = w;
    __syncthreads();
    if (tid == 0)
        atomicAdd(out, (ss[0] + ss[1] + ss[2] + ss[3]) * (1.0f / (float)(BATCH * NPTS)));
}

extern "C" void kernel_launch(void* const* d_in, const int* in_sizes, int n_in,
                              void* d_out, int out_size, void* d_ws, size_t ws_size,
                              hipStream_t stream) {
    const float* x = (const float*)d_in[0];
    const float* y = (const float*)d_in[1];
    float* out = (float*)d_out;
    float* partial = (float*)d_ws;            // 2*4*8*8192*4 = 2 MB

    hipMemsetAsync(out, 0, sizeof(float), stream);
    chamfer_mfma<<<dim3(BANDS, BATCH * SLICES, 2), TPB, 0, stream>>>(x, y, partial);
    chamfer_reduce<<<dim3(2 * BATCH * NPTS / TPB), TPB, 0, stream>>>(partial, out);
}